// Round 2
// baseline (756.868 us; speedup 1.0000x reference)
//
#include <hip/hip_runtime.h>

typedef __bf16 bf16;
typedef __bf16 bf16x4 __attribute__((ext_vector_type(4)));
typedef __bf16 bf16x8 __attribute__((ext_vector_type(8)));
typedef float f32x4 __attribute__((ext_vector_type(4)));

#define LOG2E 1.4426950408889634f

// ---------------------------------------------------------------------------
// Projection: Out = X @ W^T + bias.  X:[4096,1024] f32, W:[1024,1024] f32.
// z=0 -> Q' (bf16, [4096,1024]), z=1 -> K' (same), z=2 -> V'^T per head:
//   vt[(b*1024 + n)*2048 + s]   (n = h*64+d), so attention can read V^T rows
//   with contiguous s (kk) for the MFMA B-operand layout.
// Software-pipelined: global loads for k+1 issued while MFMAing tile k.
// ---------------------------------------------------------------------------
__global__ __launch_bounds__(256, 3)
void proj_kernel(const float* __restrict__ Xq, const float* __restrict__ Xk,
                 const float* __restrict__ Xv,
                 const float* __restrict__ Wq, const float* __restrict__ Wk,
                 const float* __restrict__ Wv,
                 const float* __restrict__ Bq, const float* __restrict__ Bk,
                 const float* __restrict__ Bv,
                 bf16* __restrict__ Oq, bf16* __restrict__ Ok,
                 bf16* __restrict__ Ov)
{
    const int z = blockIdx.z;
    const float* X  = (z == 0) ? Xq : (z == 1) ? Xk : Xv;
    const float* W  = (z == 0) ? Wq : (z == 1) ? Wk : Wv;
    const float* Bi = (z == 0) ? Bq : (z == 1) ? Bk : Bv;

    const int n0 = blockIdx.x * 128;
    const int m0 = blockIdx.y * 128;

    // +8 pad on 32-col rows: 40 elems -> 80B row stride, 16B-aligned frag reads.
    __shared__ bf16 As[128 * 40];
    __shared__ bf16 Bs[128 * 40];

    const int t = threadIdx.x;
    const int w = t >> 6, l = t & 63, quad = l >> 4, ln = l & 15;
    const int wm = (w & 1) * 64, wn = (w >> 1) * 64;

    const f32x4 zero4 = {0.f, 0.f, 0.f, 0.f};
    f32x4 acc[4][4];
    for (int mi = 0; mi < 4; mi++)
        for (int ni = 0; ni < 4; ni++) acc[mi][ni] = zero4;

    // staging slot for this thread: 4 iters x (1 float4 of X + 1 of W)
    int srow[4], sc4[4];
    for (int i = 0; i < 4; i++) {
        int idx = i * 256 + t;
        srow[i] = idx >> 3; sc4[i] = idx & 7;
    }

    float4 ra[4], rb[4];
    for (int i = 0; i < 4; i++) {
        ra[i] = *(const float4*)&X[(size_t)(m0 + srow[i]) * 1024 + sc4[i] * 4];
        rb[i] = *(const float4*)&W[(size_t)(n0 + srow[i]) * 1024 + sc4[i] * 4];
    }

    for (int k0 = 0; k0 < 1024; k0 += 32) {
        if (k0) __syncthreads();          // prev tile's LDS reads complete
        for (int i = 0; i < 4; i++) {
            bf16x4 av, bv;
            av[0] = (bf16)ra[i].x; av[1] = (bf16)ra[i].y;
            av[2] = (bf16)ra[i].z; av[3] = (bf16)ra[i].w;
            bv[0] = (bf16)rb[i].x; bv[1] = (bf16)rb[i].y;
            bv[2] = (bf16)rb[i].z; bv[3] = (bf16)rb[i].w;
            *(bf16x4*)&As[srow[i] * 40 + sc4[i] * 4] = av;
            *(bf16x4*)&Bs[srow[i] * 40 + sc4[i] * 4] = bv;
        }
        __syncthreads();

        if (k0 + 32 < 1024) {             // prefetch next tile during MFMA
            for (int i = 0; i < 4; i++) {
                ra[i] = *(const float4*)&X[(size_t)(m0 + srow[i]) * 1024 + k0 + 32 + sc4[i] * 4];
                rb[i] = *(const float4*)&W[(size_t)(n0 + srow[i]) * 1024 + k0 + 32 + sc4[i] * 4];
            }
        }

        bf16x8 af[4], bfv[4];
        for (int mi = 0; mi < 4; mi++)
            af[mi] = *(const bf16x8*)&As[(wm + mi * 16 + ln) * 40 + quad * 8];
        for (int ni = 0; ni < 4; ni++)
            bfv[ni] = *(const bf16x8*)&Bs[(wn + ni * 16 + ln) * 40 + quad * 8];
        for (int mi = 0; mi < 4; mi++)
            for (int ni = 0; ni < 4; ni++)
                acc[mi][ni] = __builtin_amdgcn_mfma_f32_16x16x32_bf16(
                    af[mi], bfv[ni], acc[mi][ni], 0, 0, 0);
    }

    // epilogue: C/D layout col = ln, row = quad*4 + r
    bf16* Onat = (z == 0) ? Oq : Ok;
    for (int ni = 0; ni < 4; ni++) {
        int n = n0 + wn + ni * 16 + ln;
        float bias = Bi[n];
        for (int mi = 0; mi < 4; mi++) {
            int mbase = m0 + wm + mi * 16 + quad * 4;
            if (z < 2) {
                for (int r = 0; r < 4; r++)
                    Onat[(size_t)(mbase + r) * 1024 + n] = (bf16)(acc[mi][ni][r] + bias);
            } else {
                int b = mbase >> 11, s0 = mbase & 2047;
                bf16x4 vv;
                for (int r = 0; r < 4; r++) vv[r] = (bf16)(acc[mi][ni][r] + bias);
                *(bf16x4*)&Ov[(size_t)(b * 1024 + n) * 2048 + s0] = vv;
            }
        }
    }
}

// ---------------------------------------------------------------------------
// Fused flash attention that also streams raw (scale+mask) scores to d_out.
// Block = (q-tile of 64 rows, head h, batch b); 4 waves, wave w owns rows
// [w*16, w*16+16). K-tile BN=64 per iteration, 32 iterations.
// LDS 37 KB -> 4 blocks/CU; next K/V tile register-prefetched during compute.
// ---------------------------------------------------------------------------
__global__ __launch_bounds__(256, 4)
void attn_kernel(const bf16* __restrict__ Qp, const bf16* __restrict__ Kp,
                 const bf16* __restrict__ Vt, const float* __restrict__ mask,
                 float* __restrict__ ctx, float* __restrict__ scores)
{
    const int qt = blockIdx.x, h = blockIdx.y, b = blockIdx.z;
    const int q0 = qt * 64;
    const int t = threadIdx.x, w = t >> 6, l = t & 63, quad = l >> 4, ln = l & 15;

    __shared__ bf16 Qs[64 * 72];    // [q][d]   ld=72
    __shared__ bf16 Ks[64 * 72];    // [kk][d]
    __shared__ bf16 VTs[64 * 72];   // [d][kk]
    __shared__ bf16 Ps[64 * 72];    // [q][kk]  (same-wave rows only)

    int srow[2], sd8[2];
    for (int i = 0; i < 2; i++) {
        int idx = i * 256 + t;
        srow[i] = idx >> 3; sd8[i] = idx & 7;
    }

    // stage Q tile [64 x 64] once
    for (int i = 0; i < 2; i++)
        *(bf16x8*)&Qs[srow[i] * 72 + sd8[i] * 8] =
            *(const bf16x8*)&Qp[(size_t)(b * 2048 + q0 + srow[i]) * 1024 + h * 64 + sd8[i] * 8];

    // prefetch kt=0 K / V^T tiles into registers
    bf16x8 kr[2], vrr[2];
    for (int i = 0; i < 2; i++) {
        kr[i]  = *(const bf16x8*)&Kp[(size_t)(b * 2048 + srow[i]) * 1024 + h * 64 + sd8[i] * 8];
        vrr[i] = *(const bf16x8*)&Vt[(size_t)(b * 1024 + h * 64 + srow[i]) * 2048 + sd8[i] * 8];
    }
    __syncthreads();

    bf16x8 aq[2];
    for (int ks = 0; ks < 2; ks++)
        aq[ks] = *(const bf16x8*)&Qs[(w * 16 + ln) * 72 + ks * 32 + quad * 8];

    const f32x4 zero4 = {0.f, 0.f, 0.f, 0.f};
    f32x4 O[4];
    for (int ni = 0; ni < 4; ni++) O[ni] = zero4;
    float mst[4], lst[4];
    for (int r = 0; r < 4; r++) { mst[r] = -1e30f; lst[r] = 0.f; }

    const int srow_base = (b * 16 + h) * 2048 + q0 + w * 16;

    for (int kt = 0; kt < 32; kt++) {
        const int kk0 = kt * 64;
        if (kt) __syncthreads();          // prev compute's LDS reads complete
        for (int i = 0; i < 2; i++) {
            *(bf16x8*)&Ks[srow[i] * 72 + sd8[i] * 8]  = kr[i];
            *(bf16x8*)&VTs[srow[i] * 72 + sd8[i] * 8] = vrr[i];
        }
        __syncthreads();

        if (kt + 1 < 32) {                // prefetch next tile during compute
            int kk0n = kk0 + 64;
            for (int i = 0; i < 2; i++) {
                kr[i]  = *(const bf16x8*)&Kp[(size_t)(b * 2048 + kk0n + srow[i]) * 1024 + h * 64 + sd8[i] * 8];
                vrr[i] = *(const bf16x8*)&Vt[(size_t)(b * 1024 + h * 64 + srow[i]) * 2048 + kk0n + sd8[i] * 8];
            }
        }

        // S = Q K^T  (A: m=ln -> q, k=quad*8+j -> d; B: n=ln -> kk)
        f32x4 sa[4];
        for (int ni = 0; ni < 4; ni++) sa[ni] = zero4;
        for (int ks = 0; ks < 2; ks++) {
            bf16x8 kf[4];
            for (int ni = 0; ni < 4; ni++)
                kf[ni] = *(const bf16x8*)&Ks[(ni * 16 + ln) * 72 + ks * 32 + quad * 8];
            for (int ni = 0; ni < 4; ni++)
                sa[ni] = __builtin_amdgcn_mfma_f32_16x16x32_bf16(
                    aq[ks], kf[ni], sa[ni], 0, 0, 0);
        }

        float maskv[4];
        for (int ni = 0; ni < 4; ni++)
            maskv[ni] = mask[b * 2048 + kk0 + ni * 16 + ln];

        // scale + mask, stream raw scores, per-row tile max
        float rmax[4];
        for (int r = 0; r < 4; r++) rmax[r] = -1e30f;
        for (int ni = 0; ni < 4; ni++) {
            int col = kk0 + ni * 16 + ln;
            for (int r = 0; r < 4; r++) {
                float v = sa[ni][r] * 0.125f + maskv[ni];
                sa[ni][r] = v;
                scores[(size_t)(srow_base + quad * 4 + r) * 2048 + col] = v;
                rmax[r] = fmaxf(rmax[r], v);
            }
        }
        for (int r = 0; r < 4; r++) {
            float v = rmax[r];
            v = fmaxf(v, __shfl_xor(v, 1));
            v = fmaxf(v, __shfl_xor(v, 2));
            v = fmaxf(v, __shfl_xor(v, 4));
            v = fmaxf(v, __shfl_xor(v, 8));
            rmax[r] = v;
        }

        // online softmax update
        float alpha[4];
        for (int r = 0; r < 4; r++) {
            float mnew = fmaxf(mst[r], rmax[r]);
            alpha[r] = exp2f((mst[r] - mnew) * LOG2E);
            mst[r] = mnew;
        }

        float rsum[4];
        for (int r = 0; r < 4; r++) rsum[r] = 0.f;
        for (int ni = 0; ni < 4; ni++)
            for (int r = 0; r < 4; r++) {
                float p = exp2f((sa[ni][r] - mst[r]) * LOG2E);
                rsum[r] += p;
                Ps[(w * 16 + quad * 4 + r) * 72 + ni * 16 + ln] = (bf16)p;
            }
        for (int r = 0; r < 4; r++) {
            float v = rsum[r];
            v += __shfl_xor(v, 1);
            v += __shfl_xor(v, 2);
            v += __shfl_xor(v, 4);
            v += __shfl_xor(v, 8);
            lst[r] = lst[r] * alpha[r] + v;
        }

        for (int ni = 0; ni < 4; ni++)
            for (int r = 0; r < 4; r++) O[ni][r] *= alpha[r];

        // O += P V  (A: m=ln -> q, k -> kk; B: n=ln -> d, k -> kk from V^T)
        for (int ks = 0; ks < 2; ks++) {
            bf16x8 pf, vf[4];
            pf = *(const bf16x8*)&Ps[(w * 16 + ln) * 72 + ks * 32 + quad * 8];
            for (int ni = 0; ni < 4; ni++)
                vf[ni] = *(const bf16x8*)&VTs[(ni * 16 + ln) * 72 + ks * 32 + quad * 8];
            for (int ni = 0; ni < 4; ni++)
                O[ni] = __builtin_amdgcn_mfma_f32_16x16x32_bf16(
                    pf, vf[ni], O[ni], 0, 0, 0);
        }
    }

    // epilogue: ctx = O / l
    for (int ni = 0; ni < 4; ni++) {
        int n = h * 64 + ni * 16 + ln;
        for (int r = 0; r < 4; r++) {
            int row = b * 2048 + q0 + w * 16 + quad * 4 + r;
            ctx[(size_t)row * 1024 + n] = O[ni][r] / lst[r];
        }
    }
}

extern "C" void kernel_launch(void* const* d_in, const int* in_sizes, int n_in,
                              void* d_out, int out_size, void* d_ws, size_t ws_size,
                              hipStream_t stream) {
    const float* q    = (const float*)d_in[0];
    const float* k    = (const float*)d_in[1];
    const float* v    = (const float*)d_in[2];
    const float* mask = (const float*)d_in[3];
    const float* Wq   = (const float*)d_in[4];
    const float* bq   = (const float*)d_in[5];
    const float* Wk   = (const float*)d_in[6];
    const float* bk   = (const float*)d_in[7];
    const float* Wv   = (const float*)d_in[8];
    const float* bv   = (const float*)d_in[9];

    bf16* Qp = (bf16*)d_ws;                 // [4096,1024]
    bf16* Kp = Qp + (size_t)4096 * 1024;    // [4096,1024]
    bf16* Vt = Kp + (size_t)4096 * 1024;    // [B*1024, 2048] = V'^T per head

    float* ctx    = (float*)d_out;                    // [2,2048,1024]
    float* scores = ctx + (size_t)2 * 2048 * 1024;    // [2,16,2048,2048]

    proj_kernel<<<dim3(8, 32, 3), 256, 0, stream>>>(
        q, k, v, Wq, Wk, Wv, bq, bk, bv, Qp, Kp, Vt);
    attn_kernel<<<dim3(32, 16, 2), 256, 0, stream>>>(
        Qp, Kp, Vt, mask, ctx, scores);
}